// Round 9
// baseline (72.479 us; speedup 1.0000x reference)
//
#include <hip/hip_runtime.h>

typedef float f32x4 __attribute__((ext_vector_type(4)));

#define WAVE 64
#define CHUNK 256   // samples per wave

__device__ __forceinline__ void ntst4(float* p, float x, float y, float z, float w) {
    f32x4 v = {x, y, z, w};
    __builtin_nontemporal_store(v, (f32x4*)p);
}

// Kernel 1: packed segment bounds + per-ray output init (bg=1, sums=0; empty rays keep these).
__global__ __launch_bounds__(256) void seg_init_kernel(
    const int* __restrict__ ray_id, int n, int R, int* __restrict__ seg_se,
    float* __restrict__ out_bg, float* __restrict__ out_i3,
    float* __restrict__ out_i1, float* __restrict__ out_spr)
{
    int i = blockIdx.x * blockDim.x + threadIdx.x;
    if (i < n) {
        int rid = ray_id[i];
        if (i == 0 || ray_id[i - 1] != rid) seg_se[2 * rid + 0] = i;
        if (i == n - 1 || ray_id[i + 1] != rid) seg_se[2 * rid + 1] = i + 1;
    }
    if (i < R) {
        out_bg[i] = 1.0f;
        out_i1[i] = 0.0f;
        out_i3[3 * i + 0] = 0.f; out_i3[3 * i + 1] = 0.f; out_i3[3 * i + 2] = 0.f;
        out_spr[3 * i + 0] = 0.f; out_spr[3 * i + 1] = 0.f; out_spr[3 * i + 2] = 0.f;
    }
}

// Kernel 2: H[k] = first segment head >= k*CHUNK; H[nchunk] = n.
__global__ __launch_bounds__(256) void chunk_head_kernel(
    const int* __restrict__ ray_id, const int* __restrict__ seg_se,
    int* __restrict__ H, int nchunk, int n)
{
    int k = blockIdx.x * blockDim.x + threadIdx.x;
    if (k > nchunk) return;
    if (k == nchunk) { H[k] = n; return; }
    int cs = k * CHUNK;
    int r = ray_id[cs];
    int2 se = *(const int2*)(seg_se + 2 * r);
    H[k] = (se.x == cs) ? cs : se.y;
}

// Kernel 3: dense per-chunk segmented scan. Wave k owns samples [H[k], H[k+1])
// (whole segments only). Sweep 1: 9-channel segmented scan -> T, bg, per-ray
// sums (global) + spr triple into LDS per local segment index. Sweep 2:
// count-scan only -> sps broadcast from LDS, dense stores.
__global__ __launch_bounds__(256) void vr_kernel(
    const float* __restrict__ alpha,
    const float* __restrict__ values3d,
    const float* __restrict__ values1d,
    const float* __restrict__ weights,
    const float* __restrict__ sample_values,
    const int*   __restrict__ ray_id,
    const int*   __restrict__ H,
    float* __restrict__ out_T,
    float* __restrict__ out_bg,
    float* __restrict__ out_i3,
    float* __restrict__ out_i1,
    float* __restrict__ out_spr,
    float* __restrict__ out_sps,
    int n, int nchunk)
{
    __shared__ float sprl[4][CHUNK * 3];   // per-wave local segment sums (<=256 segs/wave)

    const int lane = threadIdx.x & 63;
    const int wid  = threadIdx.x >> 6;
    const int k    = blockIdx.x * 4 + wid;

    int A = 0, B = 0;
    if (k < nchunk) { A = H[k]; B = H[k + 1]; }
    const int A4  = A & ~3;
    const int nm4 = n - 4;

    // sweep-1 carry (wave-uniform values held per-lane)
    int   gC = 0;  int prevrid = -1;
    float gP = 1.f, gI1 = 0.f, gAX = 0.f, gAY = 0.f, gAZ = 0.f,
          gBX = 0.f, gBY = 0.f, gBZ = 0.f;

    if (A < B)
    for (int p = A4; p < B; p += 4 * WAVE) {
        const int a  = p + 4 * lane;          // 4-aligned; a<n => a<=n-4, loads safe
        const int al = min(a, nm4);

        const int4  rd = *(const int4*)(ray_id + al);
        const f32x4 av = *(const f32x4*)(alpha + al);
        const f32x4 wv = *(const f32x4*)(weights + al);
        const f32x4 v1 = *(const f32x4*)(values1d + al);
        const f32x4 b0 = *(const f32x4*)(values3d + 3 * (size_t)al);
        const f32x4 b1 = *(const f32x4*)(values3d + 3 * (size_t)al + 4);
        const f32x4 b2 = *(const f32x4*)(values3d + 3 * (size_t)al + 8);
        const f32x4 q0 = *(const f32x4*)(sample_values + 3 * (size_t)al);
        const f32x4 q1 = *(const f32x4*)(sample_values + 3 * (size_t)al + 4);
        const f32x4 q2 = *(const f32x4*)(sample_values + 3 * (size_t)al + 8);

        int pr = __shfl_up(rd.w, 1);
        if (lane == 0) pr = prevrid;
        int nxt = __shfl_down(rd.x, 1);
        if (lane == 63) nxt = (a + 4 < n) ? ray_id[a + 4] : -1;

        const int   rids[4] = {rd.x, rd.y, rd.z, rd.w};
        const int   prs[4]  = {pr, rd.x, rd.y, rd.z};
        const int   nxts[4] = {rd.y, rd.z, rd.w, nxt};
        const float avs[4]  = {av.x, av.y, av.z, av.w};
        const float wvs[4]  = {wv.x, wv.y, wv.z, wv.w};
        const float v1s[4]  = {v1.x, v1.y, v1.z, v1.w};
        const float v3xs[4] = {b0.x, b0.w, b1.z, b2.y};
        const float v3ys[4] = {b0.y, b1.x, b1.w, b2.z};
        const float v3zs[4] = {b0.z, b1.y, b2.x, b2.w};
        const float svxs[4] = {q0.x, q0.w, q1.z, q2.y};
        const float svys[4] = {q0.y, q1.x, q1.w, q2.z};
        const float svzs[4] = {q0.z, q1.y, q2.x, q2.w};

        bool f[4], t[4], act[4];
        float v[4], ci[4], cax[4], cay[4], caz[4], cbx[4], cby[4], cbz[4];
        #pragma unroll
        for (int e = 0; e < 4; ++e) {
            const int q = a + e;
            act[e] = (q >= A) & (q < B);
            f[e] = act[e] & ((q == A) | (rids[e] != prs[e]));
            t[e] = act[e] & ((q == B - 1) | (nxts[e] != rids[e]));
            const float om = fminf(fmaxf(1.0f - avs[e], 1e-7f), 1.0f);
            v[e] = act[e] ? om : 1.0f;
            const float W = act[e] ? wvs[e] : 0.0f;
            ci[e]  = v1s[e] * W;
            cax[e] = v3xs[e] * W;
            cay[e] = v3ys[e] * W;
            caz[e] = v3zs[e] * W;
            cbx[e] = act[e] ? svxs[e] : 0.0f;
            cby[e] = act[e] ? svys[e] : 0.0f;
            cbz[e] = act[e] ? svzs[e] : 0.0f;
        }

        // lane summary under segmented monoid
        int   sC = 0;
        float sP = 1.f, sI1 = 0.f, sAX = 0.f, sAY = 0.f, sAZ = 0.f,
              sBX = 0.f, sBY = 0.f, sBZ = 0.f;
        #pragma unroll
        for (int e = 0; e < 4; ++e) {
            sP  = f[e] ? v[e]   : sP * v[e];
            sI1 = f[e] ? ci[e]  : sI1 + ci[e];
            sAX = f[e] ? cax[e] : sAX + cax[e];
            sAY = f[e] ? cay[e] : sAY + cay[e];
            sAZ = f[e] ? caz[e] : sAZ + caz[e];
            sBX = f[e] ? cbx[e] : sBX + cbx[e];
            sBY = f[e] ? cby[e] : sBY + cby[e];
            sBZ = f[e] ? cbz[e] : sBZ + cbz[e];
            sC += (int)f[e];
        }

        // inclusive segmented scan across 64 lanes
        #pragma unroll
        for (int d = 1; d < 64; d <<= 1) {
            const int   uC  = __shfl_up(sC, d);
            const float uP  = __shfl_up(sP, d);
            const float uI  = __shfl_up(sI1, d);
            const float uAX = __shfl_up(sAX, d);
            const float uAY = __shfl_up(sAY, d);
            const float uAZ = __shfl_up(sAZ, d);
            const float uBX = __shfl_up(sBX, d);
            const float uBY = __shfl_up(sBY, d);
            const float uBZ = __shfl_up(sBZ, d);
            if (lane >= d) {
                const bool rst = sC > 0;
                sP  = rst ? sP  : uP * sP;
                sI1 = rst ? sI1 : uI + sI1;
                sAX = rst ? sAX : uAX + sAX;
                sAY = rst ? sAY : uAY + sAY;
                sAZ = rst ? sAZ : uAZ + sAZ;
                sBX = rst ? sBX : uBX + sBX;
                sBY = rst ? sBY : uBY + sBY;
                sBZ = rst ? sBZ : uBZ + sBZ;
                sC += uC;
            }
        }

        // incoming state = carry ∘ incl(lane-1)
        const int   xC  = __shfl_up(sC, 1);
        const float xP  = __shfl_up(sP, 1);
        const float xI  = __shfl_up(sI1, 1);
        const float xAX = __shfl_up(sAX, 1);
        const float xAY = __shfl_up(sAY, 1);
        const float xAZ = __shfl_up(sAZ, 1);
        const float xBX = __shfl_up(sBX, 1);
        const float xBY = __shfl_up(sBY, 1);
        const float xBZ = __shfl_up(sBZ, 1);

        int C_run; float P_run, I_run, AXr, AYr, AZr, BXr, BYr, BZr;
        if (lane == 0) {
            C_run = gC; P_run = gP; I_run = gI1;
            AXr = gAX; AYr = gAY; AZr = gAZ; BXr = gBX; BYr = gBY; BZr = gBZ;
        } else {
            const bool rst = xC > 0;
            C_run = gC + xC;
            P_run = rst ? xP  : gP * xP;
            I_run = rst ? xI  : gI1 + xI;
            AXr   = rst ? xAX : gAX + xAX;
            AYr   = rst ? xAY : gAY + xAY;
            AZr   = rst ? xAZ : gAZ + xAZ;
            BXr   = rst ? xBX : gBX + xBX;
            BYr   = rst ? xBY : gBY + xBY;
            BZr   = rst ? xBZ : gBZ + xBZ;
        }

        // serial walk: T values, tail stores
        float tv[4];
        #pragma unroll
        for (int e = 0; e < 4; ++e) {
            tv[e] = f[e] ? 1.0f : P_run;
            P_run = f[e] ? v[e]   : P_run * v[e];
            I_run = f[e] ? ci[e]  : I_run + ci[e];
            AXr   = f[e] ? cax[e] : AXr + cax[e];
            AYr   = f[e] ? cay[e] : AYr + cay[e];
            AZr   = f[e] ? caz[e] : AZr + caz[e];
            BXr   = f[e] ? cbx[e] : BXr + cbx[e];
            BYr   = f[e] ? cby[e] : BYr + cby[e];
            BZr   = f[e] ? cbz[e] : BZr + cbz[e];
            C_run += (int)f[e];
            if (t[e]) {
                const int r = rids[e];
                out_bg[r] = P_run;
                out_i1[r] = I_run;
                out_i3[3 * r + 0] = AXr; out_i3[3 * r + 1] = AYr; out_i3[3 * r + 2] = AZr;
                out_spr[3 * r + 0] = BXr; out_spr[3 * r + 1] = BYr; out_spr[3 * r + 2] = BZr;
                const int si = C_run - 1;
                sprl[wid][3 * si + 0] = BXr;
                sprl[wid][3 * si + 1] = BYr;
                sprl[wid][3 * si + 2] = BZr;
            }
        }

        if (act[0] & act[1] & act[2] & act[3]) {
            ntst4(out_T + a, tv[0], tv[1], tv[2], tv[3]);
        } else {
            if (act[0]) out_T[a + 0] = tv[0];
            if (act[1]) out_T[a + 1] = tv[1];
            if (act[2]) out_T[a + 2] = tv[2];
            if (act[3]) out_T[a + 3] = tv[3];
        }

        // carry = lane 63 post-walk state
        gC  = __shfl(C_run, 63);
        gP  = __shfl(P_run, 63);
        gI1 = __shfl(I_run, 63);
        gAX = __shfl(AXr, 63); gAY = __shfl(AYr, 63); gAZ = __shfl(AZr, 63);
        gBX = __shfl(BXr, 63); gBY = __shfl(BYr, 63); gBZ = __shfl(BZr, 63);
        prevrid = __shfl(rd.w, 63);
    }

    __syncthreads();

    // sweep 2: sps broadcast from LDS (count-scan only)
    int g2C = 0, prevrid2 = -1;
    if (A < B)
    for (int p = A4; p < B; p += 4 * WAVE) {
        const int a  = p + 4 * lane;
        const int al = min(a, nm4);
        const int4 rd = *(const int4*)(ray_id + al);

        int pr = __shfl_up(rd.w, 1);
        if (lane == 0) pr = prevrid2;

        const int rids[4] = {rd.x, rd.y, rd.z, rd.w};
        const int prs[4]  = {pr, rd.x, rd.y, rd.z};

        bool f[4], act[4];
        #pragma unroll
        for (int e = 0; e < 4; ++e) {
            const int q = a + e;
            act[e] = (q >= A) & (q < B);
            f[e] = act[e] & ((q == A) | (rids[e] != prs[e]));
        }

        int sC2 = (int)f[0] + (int)f[1] + (int)f[2] + (int)f[3];
        #pragma unroll
        for (int d = 1; d < 64; d <<= 1) {
            const int u = __shfl_up(sC2, d);
            if (lane >= d) sC2 += u;
        }
        const int x2 = __shfl_up(sC2, 1);
        int C2 = (lane == 0) ? g2C : g2C + x2;

        float gx[4], gy[4], gz[4];
        #pragma unroll
        for (int e = 0; e < 4; ++e) {
            C2 += (int)f[e];
            const int si = C2 - 1;
            if (act[e]) {
                gx[e] = sprl[wid][3 * si + 0];
                gy[e] = sprl[wid][3 * si + 1];
                gz[e] = sprl[wid][3 * si + 2];
            } else {
                gx[e] = 0.f; gy[e] = 0.f; gz[e] = 0.f;
            }
        }

        if (act[0] & act[1] & act[2] & act[3]) {
            ntst4(out_sps + 3 * (size_t)a + 0, gx[0], gy[0], gz[0], gx[1]);
            ntst4(out_sps + 3 * (size_t)a + 4, gy[1], gz[1], gx[2], gy[2]);
            ntst4(out_sps + 3 * (size_t)a + 8, gz[2], gx[3], gy[3], gz[3]);
        } else {
            #pragma unroll
            for (int e = 0; e < 4; ++e) {
                if (act[e]) {
                    out_sps[3 * (size_t)(a + e) + 0] = gx[e];
                    out_sps[3 * (size_t)(a + e) + 1] = gy[e];
                    out_sps[3 * (size_t)(a + e) + 2] = gz[e];
                }
            }
        }

        g2C = __shfl(C2, 63);
        prevrid2 = __shfl(rd.w, 63);
    }
}

extern "C" void kernel_launch(void* const* d_in, const int* in_sizes, int n_in,
                              void* d_out, int out_size, void* d_ws, size_t ws_size,
                              hipStream_t stream) {
    const float* alpha = (const float*)d_in[0];
    const float* v3    = (const float*)d_in[1];
    const float* v1    = (const float*)d_in[2];
    const float* w     = (const float*)d_in[3];
    const float* sv    = (const float*)d_in[4];
    const int*   rid   = (const int*)d_in[5];

    const int N = in_sizes[0];
    const int R = (out_size - 4 * N) / 8;   // out = N + R + 3R + R + 3R + 3N
    const int nchunk = (N + CHUNK - 1) / CHUNK;

    int* seg_se = (int*)d_ws;               // [R][2]
    int* Harr   = seg_se + 2 * (size_t)R;   // [nchunk+1]

    float* out     = (float*)d_out;
    float* out_T   = out;
    float* out_bg  = out + N;
    float* out_i3  = out_bg + R;
    float* out_i1  = out_i3 + 3 * (size_t)R;
    float* out_spr = out_i1 + R;
    float* out_sps = out_spr + 3 * (size_t)R;

    seg_init_kernel<<<(N + 255) / 256, 256, 0, stream>>>(
        rid, N, R, seg_se, out_bg, out_i3, out_i1, out_spr);

    chunk_head_kernel<<<(nchunk + 1 + 255) / 256, 256, 0, stream>>>(
        rid, seg_se, Harr, nchunk, N);

    const int blocks = (nchunk + 3) / 4;    // 4 waves per block, 1 chunk per wave
    vr_kernel<<<blocks, 256, 0, stream>>>(
        alpha, v3, v1, w, sv, rid, Harr,
        out_T, out_bg, out_i3, out_i1, out_spr, out_sps, N, nchunk);
}

// Round 10
// 50.003 us; speedup vs baseline: 1.4495x; 1.4495x over previous
//
#include <hip/hip_runtime.h>

typedef float f32x4 __attribute__((ext_vector_type(4)));

// ---------- cross-lane helpers (compile-time patterns) ----------
template<int CTRL>
__device__ __forceinline__ float dpp1(float x) {
    // DPP move, old = 1.0f (multiplicative identity), bound_ctrl=false.
    return __int_as_float(__builtin_amdgcn_update_dpp(
        0x3f800000, __float_as_int(x), CTRL, 0xF, 0xF, false));
}
template<int CTRL>
__device__ __forceinline__ float dpp0(float x) {
    // DPP move, additive identity: bound_ctrl=true -> out-of-row reads 0.
    return __int_as_float(__builtin_amdgcn_update_dpp(
        0, __float_as_int(x), CTRL, 0xF, 0xF, true));
}
template<int PAT>
__device__ __forceinline__ float swz(float x) {
    return __int_as_float(__builtin_amdgcn_ds_swizzle(__float_as_int(x), PAT));
}
// inclusive prefix within 16-lane row via DPP; lane 15 ends with the total
#define FUNNEL16(v) do { \
    v += dpp0<0x111>(v); \
    v += dpp0<0x112>(v); \
    v += dpp0<0x114>(v); \
    v += dpp0<0x118>(v); } while (0)

__device__ __forceinline__ void ntst4(float* p, float x, float y, float z, float w) {
    f32x4 v = {x, y, z, w};
    __builtin_nontemporal_store(v, (f32x4*)p);
}

// Kernel 1: segment bounds, int4-vectorized. seg_se[2r]=start, seg_se[2r+1]=end.
// NOTE: entries for empty rays are never written; ray_kernel sanitizes.
__global__ __launch_bounds__(256) void seg_bounds_kernel(
    const int* __restrict__ ray_id, int n, int* __restrict__ seg_se)
{
    const int t = blockIdx.x * blockDim.x + threadIdx.x;
    const int a = t * 4;
    if (a >= n) return;            // n % 4 == 0
    const int4 rv = *(const int4*)(ray_id + a);
    const int prev = (a == 0) ? -1 : ray_id[a - 1];
    const int nxt  = (a + 4 < n) ? ray_id[a + 4] : -1;

    if (rv.x != prev) seg_se[2 * rv.x] = a;
    if (rv.y != rv.x) { seg_se[2 * rv.x + 1] = a + 1; seg_se[2 * rv.y] = a + 1; }
    if (rv.z != rv.y) { seg_se[2 * rv.y + 1] = a + 2; seg_se[2 * rv.z] = a + 2; }
    if (rv.w != rv.z) { seg_se[2 * rv.z + 1] = a + 3; seg_se[2 * rv.w] = a + 3; }
    if (rv.w != nxt)  seg_se[2 * rv.w + 1] = a + 4;   // incl. a+4==n (nxt=-1)
}

// Kernel 2: 16 lanes per ray, 4 samples per lane, 4 rays/wave. Fused:
// scan + segment sums + sps broadcast.
__global__ __launch_bounds__(256) void ray_kernel(
    const float* __restrict__ alpha,
    const float* __restrict__ values3d,
    const float* __restrict__ values1d,
    const float* __restrict__ weights,
    const float* __restrict__ sample_values,
    const int*   __restrict__ ray_id,
    const int*   __restrict__ seg_se,
    float* __restrict__ out_T,    // [N]
    float* __restrict__ out_bg,   // [R]
    float* __restrict__ out_i3,   // [R,3]
    float* __restrict__ out_i1,   // [R]
    float* __restrict__ out_spr,  // [R,3]
    float* __restrict__ out_sps,  // [N,3]
    int R, int N)
{
    const int lane = threadIdx.x & 63;
    const int wid  = threadIdx.x >> 6;
    const int j    = lane & 15;              // lane within 16-lane group
    const int g    = lane >> 4;              // group (ray slot) 0..3
    const int r    = (blockIdx.x * 4 + wid) * 4 + g;
    const bool ray_ok = (r < R);
    const int rc = ray_ok ? r : 0;

    const int2 se = ((const int2*)seg_se)[rc];   // one 8B load
    int s0 = se.x, s1 = se.y;
    // Sanitize: ws is NOT pre-zeroed. A genuine segment of ray rc satisfies
    // 0<=s0<s1<=N and ray_id[s0]==rc; no stale/garbage entry for an EMPTY ray
    // can satisfy the id check (an empty ray has no sample with its id).
    bool valid = ray_ok & (s0 >= 0) & (s0 < s1) & (s1 <= N);
    if (valid) valid = (ray_id[s0] == rc);
    if (!valid) { s0 = 0; s1 = 0; }          // -> bg=1, sums=0 (correct if empty)

    float c = 1.0f;                          // running product carry
    float i3x = 0.f, i3y = 0.f, i3z = 0.f, i1 = 0.f;
    float sx = 0.f, sy = 0.f, sz = 0.f;

    const int base0 = s0 & ~3;               // align tile grid to float4

    for (int base = base0; base < s1; base += 64) {
        const int a = base + 4 * j;          // this lane's aligned 4-sample slot
        const bool tile_ok = (a < s1);
        const int  al = tile_ok ? a : base0; // clamp to valid in-segment addr

        // ---- issue loads at iteration top ----
        const f32x4 av  = *(const f32x4*)(alpha + al);
        const f32x4 wv  = *(const f32x4*)(weights + al);
        const f32x4 v1v = *(const f32x4*)(values1d + al);
        const f32x4 b0  = *(const f32x4*)(values3d + 3 * al);
        const f32x4 b1  = *(const f32x4*)(values3d + 3 * al + 4);
        const f32x4 b2  = *(const f32x4*)(values3d + 3 * al + 8);
        const f32x4 q0  = *(const f32x4*)(sample_values + 3 * al);
        const f32x4 q1  = *(const f32x4*)(sample_values + 3 * al + 4);
        const f32x4 q2  = *(const f32x4*)(sample_values + 3 * al + 8);

        // element ownership masks
        const bool w0 = tile_ok & (a + 0 >= s0);
        const bool w1 = tile_ok & (a + 1 >= s0) & (a + 1 < s1);
        const bool w2 = tile_ok & (a + 2 >= s0) & (a + 2 < s1);
        const bool w3 = tile_ok & (a + 3 < s1);

        float o0 = fminf(fmaxf(1.0f - av.x, 1e-7f), 1.0f); if (!w0) o0 = 1.0f;
        float o1 = fminf(fmaxf(1.0f - av.y, 1e-7f), 1.0f); if (!w1) o1 = 1.0f;
        float o2 = fminf(fmaxf(1.0f - av.z, 1e-7f), 1.0f); if (!w2) o2 = 1.0f;
        float o3 = fminf(fmaxf(1.0f - av.w, 1e-7f), 1.0f); if (!w3) o3 = 1.0f;

        const float p01  = o0 * o1;
        const float p012 = p01 * o2;
        float p = p012 * o3;                 // lane-local product

        // inclusive multiplicative scan across the 16-lane row (DPP)
        p *= dpp1<0x111>(p);                 // row_shr:1
        p *= dpp1<0x112>(p);                 // row_shr:2
        p *= dpp1<0x114>(p);                 // row_shr:4
        p *= dpp1<0x118>(p);                 // row_shr:8
        const float gincl = p;
        const float gexcl = dpp1<0x111>(gincl);  // lane j=0 gets 1.0

        const float cg = c * gexcl;
        const float t0 = cg;
        const float t1 = cg * o0;
        const float t2 = cg * p01;
        const float t3 = cg * p012;

        // accumulate (masked)
        const float W0 = w0 ? wv.x : 0.f;
        const float W1 = w1 ? wv.y : 0.f;
        const float W2 = w2 ? wv.z : 0.f;
        const float W3 = w3 ? wv.w : 0.f;
        const float M0 = w0 ? 1.f : 0.f;
        const float M1 = w1 ? 1.f : 0.f;
        const float M2 = w2 ? 1.f : 0.f;
        const float M3 = w3 ? 1.f : 0.f;

        i1  += v1v.x * W0 + v1v.y * W1 + v1v.z * W2 + v1v.w * W3;
        i3x += b0.x * W0 + b0.w * W1 + b1.z * W2 + b2.y * W3;
        i3y += b0.y * W0 + b1.x * W1 + b1.w * W2 + b2.z * W3;
        i3z += b0.z * W0 + b1.y * W1 + b2.x * W2 + b2.w * W3;
        sx  += q0.x * M0 + q0.w * M1 + q1.z * M2 + q2.y * M3;
        sy  += q0.y * M0 + q1.x * M1 + q1.w * M2 + q2.z * M3;
        sz  += q0.z * M0 + q1.y * M1 + q2.x * M2 + q2.w * M3;

        // T stores: NT only on dense full-tile path (full cache lines)
        if (w0 & w1 & w2 & w3) {
            ntst4(out_T + a, t0, t1, t2, t3);
        } else {
            if (w0) out_T[a + 0] = t0;
            if (w1) out_T[a + 1] = t1;
            if (w2) out_T[a + 2] = t2;
            if (w3) out_T[a + 3] = t3;
        }

        // carry: chunk total lives in lane 15 of the group
        c *= swz<0x1F0>(gincl);              // bcast group-lane-15
    }

    // reduce all 7 channels on the DPP/VALU pipe (total lands in lane 15)
    FUNNEL16(i3x); FUNNEL16(i3y); FUNNEL16(i3z); FUNNEL16(i1);
    FUNNEL16(sx);  FUNNEL16(sy);  FUNNEL16(sz);
    // broadcast lane-15 totals of s* to the whole group for pass 2
    sx = swz<0x1F0>(sx);
    sy = swz<0x1F0>(sy);
    sz = swz<0x1F0>(sz);

    if (ray_ok && j == 15) {
        out_bg[r] = c;
        out_i3[3 * r + 0] = i3x;
        out_i3[3 * r + 1] = i3y;
        out_i3[3 * r + 2] = i3z;
        out_i1[r] = i1;
        out_spr[3 * r + 0] = sx;
        out_spr[3 * r + 1] = sy;
        out_spr[3 * r + 2] = sz;
    }

    // pass 2: broadcast sum_per_ray over the segment
    for (int base = base0; base < s1; base += 64) {
        const int a = base + 4 * j;
        const bool tile_ok = (a < s1);
        const bool w0 = tile_ok & (a + 0 >= s0);
        const bool w1 = tile_ok & (a + 1 >= s0) & (a + 1 < s1);
        const bool w2 = tile_ok & (a + 2 >= s0) & (a + 2 < s1);
        const bool w3 = tile_ok & (a + 3 < s1);
        if (w0 & w1 & w2 & w3) {
            ntst4(out_sps + 3 * a,     sx, sy, sz, sx);
            ntst4(out_sps + 3 * a + 4, sy, sz, sx, sy);
            ntst4(out_sps + 3 * a + 8, sz, sx, sy, sz);
        } else {
            if (w0) { out_sps[3*a+0] = sx; out_sps[3*a+1]  = sy; out_sps[3*a+2]  = sz; }
            if (w1) { out_sps[3*a+3] = sx; out_sps[3*a+4]  = sy; out_sps[3*a+5]  = sz; }
            if (w2) { out_sps[3*a+6] = sx; out_sps[3*a+7]  = sy; out_sps[3*a+8]  = sz; }
            if (w3) { out_sps[3*a+9] = sx; out_sps[3*a+10] = sy; out_sps[3*a+11] = sz; }
        }
    }
}

extern "C" void kernel_launch(void* const* d_in, const int* in_sizes, int n_in,
                              void* d_out, int out_size, void* d_ws, size_t ws_size,
                              hipStream_t stream) {
    const float* alpha = (const float*)d_in[0];
    const float* v3    = (const float*)d_in[1];
    const float* v1    = (const float*)d_in[2];
    const float* w     = (const float*)d_in[3];
    const float* sv    = (const float*)d_in[4];
    const int*   rid   = (const int*)d_in[5];

    int N = in_sizes[0];
    int R = (out_size - 4 * N) / 8;  // out = N + R + 3R + R + 3R + 3N

    int* seg_se = (int*)d_ws;        // [R][2] packed (start, end); NOT pre-zeroed

    float* out     = (float*)d_out;
    float* out_T   = out;
    float* out_bg  = out + N;
    float* out_i3  = out_bg + R;
    float* out_i1  = out_i3 + 3 * (size_t)R;
    float* out_spr = out_i1 + R;
    float* out_sps = out_spr + 3 * (size_t)R;

    const int nquad = N / 4;
    seg_bounds_kernel<<<(nquad + 255) / 256, 256, 0, stream>>>(rid, N, seg_se);

    // 4 waves/block, 4 rays/wave -> 16 rays per block
    int blocks = (R + 15) / 16;
    ray_kernel<<<blocks, 256, 0, stream>>>(alpha, v3, v1, w, sv, rid, seg_se,
                                           out_T, out_bg, out_i3, out_i1, out_spr,
                                           out_sps, R, N);
}

// Round 11
// 48.777 us; speedup vs baseline: 1.4859x; 1.0252x over previous
//
#include <hip/hip_runtime.h>

typedef float f32x4 __attribute__((ext_vector_type(4)));

// ---------- cross-lane helpers (compile-time patterns) ----------
template<int CTRL>
__device__ __forceinline__ float dpp1(float x) {
    // DPP move, old = 1.0f (multiplicative identity), bound_ctrl=false.
    return __int_as_float(__builtin_amdgcn_update_dpp(
        0x3f800000, __float_as_int(x), CTRL, 0xF, 0xF, false));
}
template<int CTRL>
__device__ __forceinline__ float dpp0(float x) {
    // DPP move, additive identity: bound_ctrl=true -> out-of-row reads 0.
    return __int_as_float(__builtin_amdgcn_update_dpp(
        0, __float_as_int(x), CTRL, 0xF, 0xF, true));
}
template<int PAT>
__device__ __forceinline__ float swz(float x) {
    return __int_as_float(__builtin_amdgcn_ds_swizzle(__float_as_int(x), PAT));
}
// inclusive prefix within 16-lane row via DPP; lane 15 ends with the total
#define FUNNEL16(v) do { \
    v += dpp0<0x111>(v); \
    v += dpp0<0x112>(v); \
    v += dpp0<0x114>(v); \
    v += dpp0<0x118>(v); } while (0)

__device__ __forceinline__ void ntst4(float* p, float x, float y, float z, float w) {
    f32x4 v = {x, y, z, w};
    __builtin_nontemporal_store(v, (f32x4*)p);
}

// Kernel 1: segment bounds, int4-vectorized. seg_se[2r]=start, seg_se[2r+1]=end.
// Entries for empty rays are never written; ray_kernel sanitizes.
__global__ __launch_bounds__(256) void seg_bounds_kernel(
    const int* __restrict__ ray_id, int n, int* __restrict__ seg_se)
{
    const int t = blockIdx.x * blockDim.x + threadIdx.x;
    const int a = t * 4;
    if (a >= n) return;            // n % 4 == 0
    const int4 rv = *(const int4*)(ray_id + a);
    const int prev = (a == 0) ? -1 : ray_id[a - 1];
    const int nxt  = (a + 4 < n) ? ray_id[a + 4] : -1;

    if (rv.x != prev) seg_se[2 * rv.x] = a;
    if (rv.y != rv.x) { seg_se[2 * rv.x + 1] = a + 1; seg_se[2 * rv.y] = a + 1; }
    if (rv.z != rv.y) { seg_se[2 * rv.y + 1] = a + 2; seg_se[2 * rv.z] = a + 2; }
    if (rv.w != rv.z) { seg_se[2 * rv.z + 1] = a + 3; seg_se[2 * rv.w] = a + 3; }
    if (rv.w != nxt)  seg_se[2 * rv.w + 1] = a + 4;   // incl. a+4==n (nxt=-1)
}

// Kernel 2: 16 lanes per ray, 4 samples per lane, 4 rays/wave, 16 rays/block.
// Fused scan + segment sums + sps broadcast. Per-ray outputs staged in LDS,
// stored with 2 coalesced wave instructions per block.
__global__ __launch_bounds__(256) void ray_kernel(
    const float* __restrict__ alpha,
    const float* __restrict__ values3d,
    const float* __restrict__ values1d,
    const float* __restrict__ weights,
    const float* __restrict__ sample_values,
    const int*   __restrict__ ray_id,
    const int*   __restrict__ seg_se,
    float* __restrict__ out_T,    // [N]
    float* __restrict__ out_bg,   // [R]
    float* __restrict__ out_i3,   // [R,3]
    float* __restrict__ out_i1,   // [R]
    float* __restrict__ out_spr,  // [R,3]
    float* __restrict__ out_sps,  // [N,3]
    int R, int N)
{
    __shared__ float prr[16][8];   // per-ray {bg, i1, i3xyz, spr xyz}

    const int lane = threadIdx.x & 63;
    const int wid  = threadIdx.x >> 6;
    const int j    = lane & 15;              // lane within 16-lane group
    const int g    = lane >> 4;              // group (ray slot in wave) 0..3
    const int slot = wid * 4 + g;            // ray slot in block 0..15
    const int r0   = blockIdx.x * 16;        // block's first ray
    const int r    = r0 + slot;
    const bool ray_ok = (r < R);
    const int rc = ray_ok ? r : 0;

    const int2 se = ((const int2*)seg_se)[rc];   // one 8B load
    int s0 = se.x, s1 = se.y;
    // Arithmetic sanitize only (no memory): bounds the loop. Stale/garbage
    // entries that pass this are neutralized by `valid` in the store masks.
    const bool arith = ray_ok & (s0 >= 0) & (s0 < s1) & (s1 <= N);
    if (!arith) { s0 = 0; s1 = 0; }

    // Validity check load: issued here, consumed only at mask time -> runs
    // concurrently with the main data loads (not serial before them).
    const int chk = ray_id[s0];
    const bool valid = arith & (chk == rc);

    float c = 1.0f;                          // running product carry
    float i3x = 0.f, i3y = 0.f, i3z = 0.f, i1 = 0.f;
    float sx = 0.f, sy = 0.f, sz = 0.f;

    const int base0 = s0 & ~3;               // align tile grid to float4

    for (int base = base0; base < s1; base += 64) {
        const int a = base + 4 * j;          // this lane's aligned 4-sample slot
        const bool tile_ok = (a < s1);
        const int  al = tile_ok ? a : base0; // clamp to valid in-segment addr

        // ---- issue loads at iteration top ----
        const f32x4 av  = *(const f32x4*)(alpha + al);
        const f32x4 wv  = *(const f32x4*)(weights + al);
        const f32x4 v1v = *(const f32x4*)(values1d + al);
        const f32x4 b0  = *(const f32x4*)(values3d + 3 * al);
        const f32x4 b1  = *(const f32x4*)(values3d + 3 * al + 4);
        const f32x4 b2  = *(const f32x4*)(values3d + 3 * al + 8);
        const f32x4 q0  = *(const f32x4*)(sample_values + 3 * al);
        const f32x4 q1  = *(const f32x4*)(sample_values + 3 * al + 4);
        const f32x4 q2  = *(const f32x4*)(sample_values + 3 * al + 8);

        // element ownership masks (valid folded in)
        const bool w0 = valid & tile_ok & (a + 0 >= s0);
        const bool w1 = valid & tile_ok & (a + 1 >= s0) & (a + 1 < s1);
        const bool w2 = valid & tile_ok & (a + 2 >= s0) & (a + 2 < s1);
        const bool w3 = valid & tile_ok & (a + 3 < s1);

        float o0 = fminf(fmaxf(1.0f - av.x, 1e-7f), 1.0f); if (!w0) o0 = 1.0f;
        float o1 = fminf(fmaxf(1.0f - av.y, 1e-7f), 1.0f); if (!w1) o1 = 1.0f;
        float o2 = fminf(fmaxf(1.0f - av.z, 1e-7f), 1.0f); if (!w2) o2 = 1.0f;
        float o3 = fminf(fmaxf(1.0f - av.w, 1e-7f), 1.0f); if (!w3) o3 = 1.0f;

        const float p01  = o0 * o1;
        const float p012 = p01 * o2;
        float p = p012 * o3;                 // lane-local product

        // inclusive multiplicative scan across the 16-lane row (DPP)
        p *= dpp1<0x111>(p);                 // row_shr:1
        p *= dpp1<0x112>(p);                 // row_shr:2
        p *= dpp1<0x114>(p);                 // row_shr:4
        p *= dpp1<0x118>(p);                 // row_shr:8
        const float gincl = p;
        const float gexcl = dpp1<0x111>(gincl);  // lane j=0 gets 1.0

        const float cg = c * gexcl;
        const float t0 = cg;
        const float t1 = cg * o0;
        const float t2 = cg * p01;
        const float t3 = cg * p012;

        // accumulate (masked)
        const float W0 = w0 ? wv.x : 0.f;
        const float W1 = w1 ? wv.y : 0.f;
        const float W2 = w2 ? wv.z : 0.f;
        const float W3 = w3 ? wv.w : 0.f;
        const float M0 = w0 ? 1.f : 0.f;
        const float M1 = w1 ? 1.f : 0.f;
        const float M2 = w2 ? 1.f : 0.f;
        const float M3 = w3 ? 1.f : 0.f;

        i1  += v1v.x * W0 + v1v.y * W1 + v1v.z * W2 + v1v.w * W3;
        i3x += b0.x * W0 + b0.w * W1 + b1.z * W2 + b2.y * W3;
        i3y += b0.y * W0 + b1.x * W1 + b1.w * W2 + b2.z * W3;
        i3z += b0.z * W0 + b1.y * W1 + b2.x * W2 + b2.w * W3;
        sx  += q0.x * M0 + q0.w * M1 + q1.z * M2 + q2.y * M3;
        sy  += q0.y * M0 + q1.x * M1 + q1.w * M2 + q2.z * M3;
        sz  += q0.z * M0 + q1.y * M1 + q2.x * M2 + q2.w * M3;

        // T stores: NT only on dense full-tile path (full cache lines)
        if (w0 & w1 & w2 & w3) {
            ntst4(out_T + a, t0, t1, t2, t3);
        } else {
            if (w0) out_T[a + 0] = t0;
            if (w1) out_T[a + 1] = t1;
            if (w2) out_T[a + 2] = t2;
            if (w3) out_T[a + 3] = t3;
        }

        // carry: chunk total lives in lane 15 of the group
        c *= swz<0x1F0>(gincl);              // bcast group-lane-15
    }

    // reduce all 7 channels on the DPP/VALU pipe (total lands in lane 15)
    FUNNEL16(i3x); FUNNEL16(i3y); FUNNEL16(i3z); FUNNEL16(i1);
    FUNNEL16(sx);  FUNNEL16(sy);  FUNNEL16(sz);
    // broadcast lane-15 totals of s* to the whole group for pass 2
    sx = swz<0x1F0>(sx);
    sy = swz<0x1F0>(sy);
    sz = swz<0x1F0>(sz);

    // stage per-ray outputs in LDS (empty/invalid rays: c=1, sums=0 -> correct)
    if (j == 15) {
        prr[slot][0] = c;
        prr[slot][1] = i1;
        prr[slot][2] = i3x; prr[slot][3] = i3y; prr[slot][4] = i3z;
        prr[slot][5] = sx;  prr[slot][6] = sy;  prr[slot][7] = sz;
    }
    __syncthreads();

    // coalesced per-ray output stores: 128 threads, 1 float each
    {
        const int t = threadIdx.x;
        if (t < 128) {
            float val; float* addr; int ridx;
            if (t < 16)      { ridx = t;            val = prr[ridx][0];          addr = out_bg  + r0 + t; }
            else if (t < 32) { ridx = t - 16;       val = prr[ridx][1];          addr = out_i1  + r0 + ridx; }
            else if (t < 80) { int s = t - 32; ridx = s / 3; val = prr[ridx][2 + s % 3]; addr = out_i3  + 3 * r0 + s; }
            else             { int s = t - 80; ridx = s / 3; val = prr[ridx][5 + s % 3]; addr = out_spr + 3 * r0 + s; }
            if (r0 + ridx < R) *addr = val;
        }
    }

    // pass 2: broadcast sum_per_ray over the segment
    for (int base = base0; base < s1; base += 64) {
        const int a = base + 4 * j;
        const bool tile_ok = (a < s1);
        const bool w0 = valid & tile_ok & (a + 0 >= s0);
        const bool w1 = valid & tile_ok & (a + 1 >= s0) & (a + 1 < s1);
        const bool w2 = valid & tile_ok & (a + 2 >= s0) & (a + 2 < s1);
        const bool w3 = valid & tile_ok & (a + 3 < s1);
        if (w0 & w1 & w2 & w3) {
            ntst4(out_sps + 3 * a,     sx, sy, sz, sx);
            ntst4(out_sps + 3 * a + 4, sy, sz, sx, sy);
            ntst4(out_sps + 3 * a + 8, sz, sx, sy, sz);
        } else {
            if (w0) { out_sps[3*a+0] = sx; out_sps[3*a+1]  = sy; out_sps[3*a+2]  = sz; }
            if (w1) { out_sps[3*a+3] = sx; out_sps[3*a+4]  = sy; out_sps[3*a+5]  = sz; }
            if (w2) { out_sps[3*a+6] = sx; out_sps[3*a+7]  = sy; out_sps[3*a+8]  = sz; }
            if (w3) { out_sps[3*a+9] = sx; out_sps[3*a+10] = sy; out_sps[3*a+11] = sz; }
        }
    }
}

extern "C" void kernel_launch(void* const* d_in, const int* in_sizes, int n_in,
                              void* d_out, int out_size, void* d_ws, size_t ws_size,
                              hipStream_t stream) {
    const float* alpha = (const float*)d_in[0];
    const float* v3    = (const float*)d_in[1];
    const float* v1    = (const float*)d_in[2];
    const float* w     = (const float*)d_in[3];
    const float* sv    = (const float*)d_in[4];
    const int*   rid   = (const int*)d_in[5];

    int N = in_sizes[0];
    int R = (out_size - 4 * N) / 8;  // out = N + R + 3R + R + 3R + 3N

    int* seg_se = (int*)d_ws;        // [R][2] packed (start, end); NOT pre-zeroed

    float* out     = (float*)d_out;
    float* out_T   = out;
    float* out_bg  = out + N;
    float* out_i3  = out_bg + R;
    float* out_i1  = out_i3 + 3 * (size_t)R;
    float* out_spr = out_i1 + R;
    float* out_sps = out_spr + 3 * (size_t)R;

    const int nquad = N / 4;
    seg_bounds_kernel<<<(nquad + 255) / 256, 256, 0, stream>>>(rid, N, seg_se);

    // 4 waves/block, 4 rays/wave -> 16 rays per block
    int blocks = (R + 15) / 16;
    ray_kernel<<<blocks, 256, 0, stream>>>(alpha, v3, v1, w, sv, rid, seg_se,
                                           out_T, out_bg, out_i3, out_i1, out_spr,
                                           out_sps, R, N);
}